// Round 1
// baseline (798.632 us; speedup 1.0000x reference)
//
#include <hip/hip_runtime.h>
#include <cstdint>

// ---------------- problem constants ----------------
#define NTOK   8192        // B*S tokens
#define HDIM   1024        // hidden
#define FDIM   2048        // intermediate
#define NEXP   8
#define RTOT   (2*NTOK)    // routed rows (every token has exactly 2 experts)
#define RPAD   128         // tile-overrun padding rows

typedef unsigned short u16;
typedef short   bf16x8 __attribute__((ext_vector_type(8)));
typedef float   f32x4  __attribute__((ext_vector_type(4)));

__device__ __forceinline__ u16 f2bf(float v) {
  union { float f; uint32_t u; } a; a.f = v;
  uint32_t r = a.u + 0x7FFFu + ((a.u >> 16) & 1u);   // RNE
  return (u16)(r >> 16);
}

// ---------------- router: logits, top-2, counts ----------------
__global__ void router_kernel(const float* __restrict__ x, const float* __restrict__ gw,
                              float* __restrict__ logits, int* __restrict__ te,
                              float* __restrict__ tw, int* __restrict__ counts) {
  int gid  = blockIdx.x * blockDim.x + threadIdx.x;
  int t    = gid >> 6;
  int lane = gid & 63;
  const float4* xr = (const float4*)(x + (size_t)t * HDIM);
  float acc[NEXP];
#pragma unroll
  for (int e = 0; e < NEXP; ++e) acc[e] = 0.f;
#pragma unroll
  for (int c = 0; c < 4; ++c) {
    float4 xv = xr[c * 64 + lane];
#pragma unroll
    for (int e = 0; e < NEXP; ++e) {
      float4 wv = ((const float4*)(gw + e * HDIM))[c * 64 + lane];
      acc[e] += xv.x * wv.x + xv.y * wv.y + xv.z * wv.z + xv.w * wv.w;
    }
  }
#pragma unroll
  for (int off = 32; off > 0; off >>= 1)
#pragma unroll
    for (int e = 0; e < NEXP; ++e) acc[e] += __shfl_xor(acc[e], off, 64);

  if (lane == 0) {
#pragma unroll
    for (int e = 0; e < NEXP; ++e) logits[(size_t)t * NEXP + e] = acc[e];
    int e1 = 0;
#pragma unroll
    for (int e = 1; e < NEXP; ++e) if (acc[e] > acc[e1]) e1 = e;
    int e2 = -1;
#pragma unroll
    for (int e = 0; e < NEXP; ++e) {
      if (e == e1) continue;
      if (e2 < 0 || acc[e] > acc[e2]) e2 = e;
    }
    float m  = fmaxf(acc[e1], acc[e2]);
    float p1 = __expf(acc[e1] - m), p2 = __expf(acc[e2] - m);
    float inv = 1.f / (p1 + p2);
    te[t * 2]     = e1;  tw[t * 2]     = p1 * inv;
    te[t * 2 + 1] = e2;  tw[t * 2 + 1] = p2 * inv;
    atomicAdd(&counts[e1], 1);
    atomicAdd(&counts[e2], 1);
  }
}

// ---------------- prefix over 8 experts ----------------
__global__ void prefix_kernel(const int* __restrict__ counts, int* __restrict__ offs,
                              int* __restrict__ cursors) {
  if (threadIdx.x == 0) {
    int s = 0;
    for (int e = 0; e < NEXP; ++e) { offs[e] = s; cursors[e] = s; s += counts[e]; }
    offs[NEXP] = s;
  }
}

// ---------------- scatter tokens into expert-sorted lists ----------------
__global__ void scatter_kernel(const int* __restrict__ te, const float* __restrict__ tw,
                               int* __restrict__ cursors, int* __restrict__ tok_ids,
                               float* __restrict__ wts) {
  int t = blockIdx.x * blockDim.x + threadIdx.x;
  if (t >= NTOK) return;
#pragma unroll
  for (int s = 0; s < 2; ++s) {
    int e = te[t * 2 + s];
    int j = atomicAdd(&cursors[e], 1);
    tok_ids[j] = t;
    wts[j] = tw[t * 2 + s];
  }
}

// ---------------- gather + cast X rows to bf16 (expert-sorted) ----------------
__global__ void gather_cast_kernel(const float* __restrict__ x, const int* __restrict__ tok_ids,
                                   u16* __restrict__ Xg) {
  int j = blockIdx.x;
  int t = tok_ids[j];
  float4 v = ((const float4*)(x + (size_t)t * HDIM))[threadIdx.x];
  ushort4 o;
  o.x = f2bf(v.x); o.y = f2bf(v.y); o.z = f2bf(v.z); o.w = f2bf(v.w);
  ((ushort4*)(Xg + (size_t)j * HDIM))[threadIdx.x] = o;
}

// ---------------- transpose + cast weights: [E][K][N] f32 -> [E][N][K] bf16 ----------------
__global__ void transpose_cast_kernel(const float* __restrict__ in, u16* __restrict__ out,
                                      int K, int N) {
  __shared__ float tile[64][65];
  const size_t mat = (size_t)K * N;
  const float* src = in + blockIdx.z * mat + (size_t)(blockIdx.y * 64) * N + blockIdx.x * 64;
  int r = threadIdx.x >> 6;    // 0..3
  int c = threadIdx.x & 63;
#pragma unroll
  for (int i = 0; i < 16; ++i)
    tile[i * 4 + r][c] = src[(size_t)(i * 4 + r) * N + c];
  __syncthreads();
  u16* dst = out + blockIdx.z * mat + (size_t)(blockIdx.x * 64) * K + blockIdx.y * 64;
#pragma unroll
  for (int i = 0; i < 16; ++i) {
    int n = i * 4 + r;
    dst[(size_t)n * K + c] = f2bf(tile[c][n]);
  }
}

// ---------------- GEMM staging: 128x64 bf16 tile via global_load_lds (width 16) ----------------
// LDS layout: elem (row,k) stored at row*64 + (k ^ ((row&7)<<3))  -> ds_read_b128 is 2-way max
__device__ __forceinline__ void stage_tile(const u16* __restrict__ src, int ld,
                                           u16* __restrict__ lds, int wave, int lane) {
#pragma unroll
  for (int i = 0; i < 4; ++i) {
    int chunk = ((i << 2) + wave) << 9;       // wave-uniform LDS base (elems)
    int flat  = chunk + (lane << 3);
    int row   = flat >> 6;
    int km    = (flat & 63) ^ ((row & 7) << 3);
    __builtin_amdgcn_global_load_lds(
        (const __attribute__((address_space(1))) uint32_t*)(src + (size_t)row * ld + km),
        (__attribute__((address_space(3))) uint32_t*)(lds + chunk),
        16, 0, 0);
  }
}

// ---------------- GEMM1: G = silu(Xg @ WgT^T) * (Xg @ WuT^T), bf16 out ----------------
__global__ __launch_bounds__(256, 2)
void gemm1_kernel(const u16* __restrict__ Xg, const u16* __restrict__ Wgt,
                  const u16* __restrict__ Wut, const int* __restrict__ offs,
                  u16* __restrict__ G) {
  const int e     = blockIdx.z;
  const int rbase = offs[e];
  const int rows  = offs[e + 1] - rbase;
  const int row0  = blockIdx.y * 128;
  if (row0 >= rows) return;
  const int n0    = blockIdx.x * 128;
  const int arow0 = rbase + row0;

  __shared__ __align__(16) u16 As[128 * 64];
  __shared__ __align__(16) u16 Bgs[128 * 64];
  __shared__ __align__(16) u16 Bus[128 * 64];

  const int tid  = threadIdx.x;
  const int wave = tid >> 6;
  const int lane = tid & 63;
  const int wm   = wave >> 1, wn = wave & 1;
  const int l15  = lane & 15, quad = lane >> 4;

  const u16* Ag = Xg  + (size_t)arow0 * HDIM;
  const u16* Bg = Wgt + (size_t)e * FDIM * HDIM + (size_t)n0 * HDIM;
  const u16* Bu = Wut + (size_t)e * FDIM * HDIM + (size_t)n0 * HDIM;

  f32x4 accg[4][4], accu[4][4];
#pragma unroll
  for (int i = 0; i < 4; ++i)
#pragma unroll
    for (int j = 0; j < 4; ++j) { accg[i][j] = (f32x4)0.f; accu[i][j] = (f32x4)0.f; }

  for (int kt = 0; kt < HDIM / 64; ++kt) {
    const int k0 = kt * 64;
    stage_tile(Ag + k0, HDIM, As,  wave, lane);
    stage_tile(Bg + k0, HDIM, Bgs, wave, lane);
    stage_tile(Bu + k0, HDIM, Bus, wave, lane);
    __syncthreads();
#pragma unroll
    for (int kk = 0; kk < 64; kk += 32) {
      bf16x8 af[4];
#pragma unroll
      for (int im = 0; im < 4; ++im) {
        int r  = wm * 64 + im * 16 + l15;
        int kq = (kk + quad * 8) ^ ((r & 7) << 3);
        af[im] = *(const bf16x8*)(As + r * 64 + kq);
      }
#pragma unroll
      for (int in = 0; in < 4; ++in) {
        int r  = wn * 64 + in * 16 + l15;
        int kq = (kk + quad * 8) ^ ((r & 7) << 3);
        bf16x8 bg = *(const bf16x8*)(Bgs + r * 64 + kq);
        bf16x8 bu = *(const bf16x8*)(Bus + r * 64 + kq);
#pragma unroll
        for (int im = 0; im < 4; ++im) {
          accg[im][in] = __builtin_amdgcn_mfma_f32_16x16x32_bf16(af[im], bg, accg[im][in], 0, 0, 0);
          accu[im][in] = __builtin_amdgcn_mfma_f32_16x16x32_bf16(af[im], bu, accu[im][in], 0, 0, 0);
        }
      }
    }
    __syncthreads();
  }

  // epilogue: silu(g)*u -> bf16 G[row][n]
#pragma unroll
  for (int im = 0; im < 4; ++im) {
#pragma unroll
    for (int rr = 0; rr < 4; ++rr) {
      int lrow = row0 + wm * 64 + im * 16 + quad * 4 + rr;
      if (lrow < rows) {
        size_t grow = (size_t)(rbase + lrow);
#pragma unroll
        for (int in = 0; in < 4; ++in) {
          float g = accg[im][in][rr];
          float u = accu[im][in][rr];
          float val = g / (1.f + __expf(-g)) * u;
          int gcol = n0 + wn * 64 + in * 16 + l15;
          G[grow * FDIM + gcol] = f2bf(val);
        }
      }
    }
  }
}

// ---------------- GEMM2: out[tok] += w * (G @ WdT^T) ----------------
__global__ __launch_bounds__(256, 2)
void gemm2_kernel(const u16* __restrict__ G, const u16* __restrict__ Wdt,
                  const int* __restrict__ offs, const int* __restrict__ tok_ids,
                  const float* __restrict__ wts, float* __restrict__ out) {
  const int e     = blockIdx.z;
  const int rbase = offs[e];
  const int rows  = offs[e + 1] - rbase;
  const int row0  = blockIdx.y * 128;
  if (row0 >= rows) return;
  const int n0    = blockIdx.x * 128;
  const int arow0 = rbase + row0;

  __shared__ __align__(16) u16 As[128 * 64];
  __shared__ __align__(16) u16 Bs[128 * 64];

  const int tid  = threadIdx.x;
  const int wave = tid >> 6;
  const int lane = tid & 63;
  const int wm   = wave >> 1, wn = wave & 1;
  const int l15  = lane & 15, quad = lane >> 4;

  const u16* Ag = G   + (size_t)arow0 * FDIM;
  const u16* Bg = Wdt + (size_t)e * HDIM * FDIM + (size_t)n0 * FDIM;

  f32x4 acc[4][4];
#pragma unroll
  for (int i = 0; i < 4; ++i)
#pragma unroll
    for (int j = 0; j < 4; ++j) acc[i][j] = (f32x4)0.f;

  for (int kt = 0; kt < FDIM / 64; ++kt) {
    const int k0 = kt * 64;
    stage_tile(Ag + k0, FDIM, As, wave, lane);
    stage_tile(Bg + k0, FDIM, Bs, wave, lane);
    __syncthreads();
#pragma unroll
    for (int kk = 0; kk < 64; kk += 32) {
      bf16x8 af[4], bf[4];
#pragma unroll
      for (int im = 0; im < 4; ++im) {
        int r  = wm * 64 + im * 16 + l15;
        int kq = (kk + quad * 8) ^ ((r & 7) << 3);
        af[im] = *(const bf16x8*)(As + r * 64 + kq);
      }
#pragma unroll
      for (int in = 0; in < 4; ++in) {
        int r  = wn * 64 + in * 16 + l15;
        int kq = (kk + quad * 8) ^ ((r & 7) << 3);
        bf[in] = *(const bf16x8*)(Bs + r * 64 + kq);
      }
#pragma unroll
      for (int in = 0; in < 4; ++in)
#pragma unroll
        for (int im = 0; im < 4; ++im)
          acc[im][in] = __builtin_amdgcn_mfma_f32_16x16x32_bf16(af[im], bf[in], acc[im][in], 0, 0, 0);
    }
    __syncthreads();
  }

#pragma unroll
  for (int im = 0; im < 4; ++im) {
#pragma unroll
    for (int rr = 0; rr < 4; ++rr) {
      int lrow = row0 + wm * 64 + im * 16 + quad * 4 + rr;
      if (lrow < rows) {
        int grow = rbase + lrow;
        int t    = tok_ids[grow];
        float w  = wts[grow];
        float* orow = out + (size_t)t * HDIM + n0 + wn * 64 + l15;
#pragma unroll
        for (int in = 0; in < 4; ++in)
          unsafeAtomicAdd(orow + in * 16, acc[im][in][rr] * w);
      }
    }
  }
}

// ---------------- launch ----------------
extern "C" void kernel_launch(void* const* d_in, const int* in_sizes, int n_in,
                              void* d_out, int out_size, void* d_ws, size_t ws_size,
                              hipStream_t stream) {
  const float* x  = (const float*)d_in[0];   // [2,4096,1024]
  const float* gw = (const float*)d_in[1];   // [8,1024]
  const float* Wg = (const float*)d_in[2];   // [8,1024,2048]
  const float* Wu = (const float*)d_in[3];   // [8,1024,2048]
  const float* Wd = (const float*)d_in[4];   // [8,2048,1024]

  float* out    = (float*)d_out;             // [8192,1024]
  float* logits = out + (size_t)NTOK * HDIM; // [8192,8]

  char* p = (char*)d_ws;
  u16* Wgt = (u16*)p;  p += (size_t)NEXP * FDIM * HDIM * 2;            // [E][F][H] bf16
  u16* Wut = (u16*)p;  p += (size_t)NEXP * FDIM * HDIM * 2;
  u16* Wdt = (u16*)p;  p += (size_t)NEXP * HDIM * FDIM * 2;            // [E][H][F] bf16
  u16* Xg  = (u16*)p;  p += (size_t)(RTOT + RPAD) * HDIM * 2;          // gathered bf16 rows
  u16* G   = (u16*)p;  p += (size_t)(RTOT + RPAD) * FDIM * 2;          // silu(g)*u, bf16
  int*   tok_ids = (int*)p;   p += (RTOT + RPAD) * 4;
  float* wts     = (float*)p; p += (RTOT + RPAD) * 4;
  int*   te      = (int*)p;   p += NTOK * 2 * 4;
  float* tw      = (float*)p; p += NTOK * 2 * 4;
  int*   counts  = (int*)p;   p += NEXP * 4;
  int*   offs    = (int*)p;   p += (NEXP + 1) * 4;
  int*   cursors = (int*)p;   p += NEXP * 4;

  hipMemsetAsync(out, 0, (size_t)NTOK * HDIM * sizeof(float), stream);
  hipMemsetAsync(counts, 0, NEXP * sizeof(int), stream);

  router_kernel<<<(NTOK * 64) / 256, 256, 0, stream>>>(x, gw, logits, te, tw, counts);
  prefix_kernel<<<1, 64, 0, stream>>>(counts, offs, cursors);
  scatter_kernel<<<NTOK / 256, 256, 0, stream>>>(te, tw, cursors, tok_ids, wts);
  gather_cast_kernel<<<RTOT, 256, 0, stream>>>(x, tok_ids, Xg);

  transpose_cast_kernel<<<dim3(FDIM / 64, HDIM / 64, NEXP), 256, 0, stream>>>(Wg, Wgt, HDIM, FDIM);
  transpose_cast_kernel<<<dim3(FDIM / 64, HDIM / 64, NEXP), 256, 0, stream>>>(Wu, Wut, HDIM, FDIM);
  transpose_cast_kernel<<<dim3(HDIM / 64, FDIM / 64, NEXP), 256, 0, stream>>>(Wd, Wdt, FDIM, HDIM);

  gemm1_kernel<<<dim3(FDIM / 128, 64, NEXP), 256, 0, stream>>>(Xg, Wgt, Wut, offs, G);
  gemm2_kernel<<<dim3(HDIM / 128, 64, NEXP), 256, 0, stream>>>(G, Wdt, offs, tok_ids, wts, out);
}

// Round 3
// 568.166 us; speedup vs baseline: 1.4056x; 1.4056x over previous
//
#include <hip/hip_runtime.h>
#include <cstdint>

// ---------------- problem constants ----------------
#define NTOK   8192        // B*S tokens
#define HDIM   1024        // hidden
#define FDIM   2048        // intermediate
#define NEXP   8
#define RTOT   (2*NTOK)    // routed rows (every token has exactly 2 experts)
#define RPAD   128         // tile-overrun padding rows

typedef unsigned short u16;
typedef short   bf16x8 __attribute__((ext_vector_type(8)));
typedef float   f32x4  __attribute__((ext_vector_type(4)));

__device__ __forceinline__ u16 f2bf(float v) {
  union { float f; uint32_t u; } a; a.f = v;
  uint32_t r = a.u + 0x7FFFu + ((a.u >> 16) & 1u);   // RNE
  return (u16)(r >> 16);
}

// ---------------- router: logits, top-2 (NO global atomics) ----------------
__global__ void router_kernel(const float* __restrict__ x, const float* __restrict__ gw,
                              float* __restrict__ logits, int* __restrict__ te,
                              float* __restrict__ tw) {
  int gid  = blockIdx.x * blockDim.x + threadIdx.x;
  int t    = gid >> 6;
  int lane = gid & 63;
  const float4* xr = (const float4*)(x + (size_t)t * HDIM);
  float acc[NEXP];
#pragma unroll
  for (int e = 0; e < NEXP; ++e) acc[e] = 0.f;
#pragma unroll
  for (int c = 0; c < 4; ++c) {
    float4 xv = xr[c * 64 + lane];
#pragma unroll
    for (int e = 0; e < NEXP; ++e) {
      float4 wv = ((const float4*)(gw + e * HDIM))[c * 64 + lane];
      acc[e] += xv.x * wv.x + xv.y * wv.y + xv.z * wv.z + xv.w * wv.w;
    }
  }
#pragma unroll
  for (int off = 32; off > 0; off >>= 1)
#pragma unroll
    for (int e = 0; e < NEXP; ++e) acc[e] += __shfl_xor(acc[e], off, 64);

  if (lane == 0) {
#pragma unroll
    for (int e = 0; e < NEXP; ++e) logits[(size_t)t * NEXP + e] = acc[e];
    int e1 = 0;
#pragma unroll
    for (int e = 1; e < NEXP; ++e) if (acc[e] > acc[e1]) e1 = e;
    int e2 = -1;
#pragma unroll
    for (int e = 0; e < NEXP; ++e) {
      if (e == e1) continue;
      if (e2 < 0 || acc[e] > acc[e2]) e2 = e;
    }
    float m  = fmaxf(acc[e1], acc[e2]);
    float p1 = __expf(acc[e1] - m), p2 = __expf(acc[e2] - m);
    float inv = 1.f / (p1 + p2);
    te[t * 2]     = e1;  tw[t * 2]     = p1 * inv;
    te[t * 2 + 1] = e2;  tw[t * 2 + 1] = p2 * inv;
  }
}

// ---------------- histogram counts: LDS bins, 8 global atomics per block ----------------
__global__ void count_kernel(const int* __restrict__ te, int* __restrict__ counts) {
  __shared__ int h[NEXP];
  if (threadIdx.x < NEXP) h[threadIdx.x] = 0;
  __syncthreads();
  const int n = 2 * NTOK;
  for (int i = blockIdx.x * blockDim.x + threadIdx.x; i < n; i += gridDim.x * blockDim.x)
    atomicAdd(&h[te[i]], 1);
  __syncthreads();
  if (threadIdx.x < NEXP) atomicAdd(&counts[threadIdx.x], h[threadIdx.x]);
}

// ---------------- prefix over 8 experts (cursors padded: 64B stride) ----------------
__global__ void prefix_kernel(const int* __restrict__ counts, int* __restrict__ offs,
                              int* __restrict__ cursors) {
  if (threadIdx.x == 0) {
    int s = 0;
    for (int e = 0; e < NEXP; ++e) { offs[e] = s; cursors[e * 16] = s; s += counts[e]; }
    offs[NEXP] = s;
  }
}

// ---------------- scatter: wave-aggregated atomics (1 atomic/wave/expert) ----------------
__global__ void scatter_kernel(const int* __restrict__ te, const float* __restrict__ tw,
                               int* __restrict__ cursors, int* __restrict__ tok_ids,
                               float* __restrict__ wts) {
  int t    = blockIdx.x * blockDim.x + threadIdx.x;
  int lane = threadIdx.x & 63;
#pragma unroll
  for (int s = 0; s < 2; ++s) {
    int   e = te[t * 2 + s];
    float w = tw[t * 2 + s];
    int pos = 0;
#pragma unroll
    for (int e0 = 0; e0 < NEXP; ++e0) {
      unsigned long long m = __ballot(e == e0);
      if (e == e0) {
        int leader = __ffsll((unsigned long long)m) - 1;
        int rank   = __popcll(m & ((1ull << lane) - 1ull));
        int b = 0;
        if (lane == leader) b = atomicAdd(&cursors[e0 * 16], (int)__popcll(m));
        b = __shfl(b, leader, 64);
        pos = b + rank;
      }
    }
    tok_ids[pos] = t;
    wts[pos] = w;
  }
}

// ---------------- gather + cast X rows to bf16 (expert-sorted) ----------------
__global__ void gather_cast_kernel(const float* __restrict__ x, const int* __restrict__ tok_ids,
                                   u16* __restrict__ Xg) {
  int j = blockIdx.x;
  int t = tok_ids[j];
  float4 v = ((const float4*)(x + (size_t)t * HDIM))[threadIdx.x];
  ushort4 o;
  o.x = f2bf(v.x); o.y = f2bf(v.y); o.z = f2bf(v.z); o.w = f2bf(v.w);
  ((ushort4*)(Xg + (size_t)j * HDIM))[threadIdx.x] = o;
}

// ---------------- transpose + cast weights: [E][K][N] f32 -> [E][N][K] bf16 ----------------
__global__ void transpose_cast_kernel(const float* __restrict__ in, u16* __restrict__ out,
                                      int K, int N) {
  __shared__ float tile[64][65];
  const size_t mat = (size_t)K * N;
  const float* src = in + blockIdx.z * mat + (size_t)(blockIdx.y * 64) * N + blockIdx.x * 64;
  int r = threadIdx.x >> 6;    // 0..3
  int c = threadIdx.x & 63;
#pragma unroll
  for (int i = 0; i < 16; ++i)
    tile[i * 4 + r][c] = src[(size_t)(i * 4 + r) * N + c];
  __syncthreads();
  u16* dst = out + blockIdx.z * mat + (size_t)(blockIdx.x * 64) * K + blockIdx.y * 64;
#pragma unroll
  for (int i = 0; i < 16; ++i) {
    int n = i * 4 + r;
    dst[(size_t)n * K + c] = f2bf(tile[c][n]);
  }
}

// ---------------- GEMM staging: 128x64 bf16 tile via global_load_lds (width 16) ----------------
// LDS layout: elem (row,k) stored at row*64 + (k ^ ((row&7)<<3))  -> ds_read_b128 is 2-way max
__device__ __forceinline__ void stage_tile(const u16* __restrict__ src, int ld,
                                           u16* __restrict__ lds, int wave, int lane) {
#pragma unroll
  for (int i = 0; i < 4; ++i) {
    int chunk = ((i << 2) + wave) << 9;       // wave-uniform LDS base (elems)
    int flat  = chunk + (lane << 3);
    int row   = flat >> 6;
    int km    = (flat & 63) ^ ((row & 7) << 3);
    __builtin_amdgcn_global_load_lds(
        (const __attribute__((address_space(1))) uint32_t*)(src + (size_t)row * ld + km),
        (__attribute__((address_space(3))) uint32_t*)(lds + chunk),
        16, 0, 0);
  }
}

// ---------------- GEMM1: G = silu(Xg @ WgT^T) * (Xg @ WuT^T), bf16 out ----------------
__global__ __launch_bounds__(256, 2)
void gemm1_kernel(const u16* __restrict__ Xg, const u16* __restrict__ Wgt,
                  const u16* __restrict__ Wut, const int* __restrict__ offs,
                  u16* __restrict__ G) {
  const int e     = blockIdx.z;
  const int rbase = offs[e];
  const int rows  = offs[e + 1] - rbase;
  const int row0  = blockIdx.y * 128;
  if (row0 >= rows) return;
  const int n0    = blockIdx.x * 128;
  const int arow0 = rbase + row0;

  __shared__ __align__(16) u16 As[128 * 64];
  __shared__ __align__(16) u16 Bgs[128 * 64];
  __shared__ __align__(16) u16 Bus[128 * 64];

  const int tid  = threadIdx.x;
  const int wave = tid >> 6;
  const int lane = tid & 63;
  const int wm   = wave >> 1, wn = wave & 1;
  const int l15  = lane & 15, quad = lane >> 4;

  const u16* Ag = Xg  + (size_t)arow0 * HDIM;
  const u16* Bg = Wgt + (size_t)e * FDIM * HDIM + (size_t)n0 * HDIM;
  const u16* Bu = Wut + (size_t)e * FDIM * HDIM + (size_t)n0 * HDIM;

  f32x4 accg[4][4], accu[4][4];
#pragma unroll
  for (int i = 0; i < 4; ++i)
#pragma unroll
    for (int j = 0; j < 4; ++j) { accg[i][j] = (f32x4)0.f; accu[i][j] = (f32x4)0.f; }

  for (int kt = 0; kt < HDIM / 64; ++kt) {
    const int k0 = kt * 64;
    stage_tile(Ag + k0, HDIM, As,  wave, lane);
    stage_tile(Bg + k0, HDIM, Bgs, wave, lane);
    stage_tile(Bu + k0, HDIM, Bus, wave, lane);
    __syncthreads();
#pragma unroll
    for (int kk = 0; kk < 64; kk += 32) {
      bf16x8 af[4];
#pragma unroll
      for (int im = 0; im < 4; ++im) {
        int r  = wm * 64 + im * 16 + l15;
        int kq = (kk + quad * 8) ^ ((r & 7) << 3);
        af[im] = *(const bf16x8*)(As + r * 64 + kq);
      }
#pragma unroll
      for (int in = 0; in < 4; ++in) {
        int r  = wn * 64 + in * 16 + l15;
        int kq = (kk + quad * 8) ^ ((r & 7) << 3);
        bf16x8 bg = *(const bf16x8*)(Bgs + r * 64 + kq);
        bf16x8 bu = *(const bf16x8*)(Bus + r * 64 + kq);
#pragma unroll
        for (int im = 0; im < 4; ++im) {
          accg[im][in] = __builtin_amdgcn_mfma_f32_16x16x32_bf16(af[im], bg, accg[im][in], 0, 0, 0);
          accu[im][in] = __builtin_amdgcn_mfma_f32_16x16x32_bf16(af[im], bu, accu[im][in], 0, 0, 0);
        }
      }
    }
    __syncthreads();
  }

  // epilogue: silu(g)*u -> bf16 G[row][n]
#pragma unroll
  for (int im = 0; im < 4; ++im) {
#pragma unroll
    for (int rr = 0; rr < 4; ++rr) {
      int lrow = row0 + wm * 64 + im * 16 + quad * 4 + rr;
      if (lrow < rows) {
        size_t grow = (size_t)(rbase + lrow);
#pragma unroll
        for (int in = 0; in < 4; ++in) {
          float g = accg[im][in][rr];
          float u = accu[im][in][rr];
          float val = g / (1.f + __expf(-g)) * u;
          int gcol = n0 + wn * 64 + in * 16 + l15;
          G[grow * FDIM + gcol] = f2bf(val);
        }
      }
    }
  }
}

// ---------------- GEMM2: out[tok] += w * (G @ WdT^T) ----------------
__global__ __launch_bounds__(256, 2)
void gemm2_kernel(const u16* __restrict__ G, const u16* __restrict__ Wdt,
                  const int* __restrict__ offs, const int* __restrict__ tok_ids,
                  const float* __restrict__ wts, float* __restrict__ out) {
  const int e     = blockIdx.z;
  const int rbase = offs[e];
  const int rows  = offs[e + 1] - rbase;
  const int row0  = blockIdx.y * 128;
  if (row0 >= rows) return;
  const int n0    = blockIdx.x * 128;
  const int arow0 = rbase + row0;

  __shared__ __align__(16) u16 As[128 * 64];
  __shared__ __align__(16) u16 Bs[128 * 64];

  const int tid  = threadIdx.x;
  const int wave = tid >> 6;
  const int lane = tid & 63;
  const int wm   = wave >> 1, wn = wave & 1;
  const int l15  = lane & 15, quad = lane >> 4;

  const u16* Ag = G   + (size_t)arow0 * FDIM;
  const u16* Bg = Wdt + (size_t)e * HDIM * FDIM + (size_t)n0 * FDIM;

  f32x4 acc[4][4];
#pragma unroll
  for (int i = 0; i < 4; ++i)
#pragma unroll
    for (int j = 0; j < 4; ++j) acc[i][j] = (f32x4)0.f;

  for (int kt = 0; kt < FDIM / 64; ++kt) {
    const int k0 = kt * 64;
    stage_tile(Ag + k0, FDIM, As, wave, lane);
    stage_tile(Bg + k0, FDIM, Bs, wave, lane);
    __syncthreads();
#pragma unroll
    for (int kk = 0; kk < 64; kk += 32) {
      bf16x8 af[4], bf[4];
#pragma unroll
      for (int im = 0; im < 4; ++im) {
        int r  = wm * 64 + im * 16 + l15;
        int kq = (kk + quad * 8) ^ ((r & 7) << 3);
        af[im] = *(const bf16x8*)(As + r * 64 + kq);
      }
#pragma unroll
      for (int in = 0; in < 4; ++in) {
        int r  = wn * 64 + in * 16 + l15;
        int kq = (kk + quad * 8) ^ ((r & 7) << 3);
        bf[in] = *(const bf16x8*)(Bs + r * 64 + kq);
      }
#pragma unroll
      for (int in = 0; in < 4; ++in)
#pragma unroll
        for (int im = 0; im < 4; ++im)
          acc[im][in] = __builtin_amdgcn_mfma_f32_16x16x32_bf16(af[im], bf[in], acc[im][in], 0, 0, 0);
    }
    __syncthreads();
  }

#pragma unroll
  for (int im = 0; im < 4; ++im) {
#pragma unroll
    for (int rr = 0; rr < 4; ++rr) {
      int lrow = row0 + wm * 64 + im * 16 + quad * 4 + rr;
      if (lrow < rows) {
        int grow = rbase + lrow;
        int t    = tok_ids[grow];
        float w  = wts[grow];
        float* orow = out + (size_t)t * HDIM + n0 + wn * 64 + l15;
#pragma unroll
        for (int in = 0; in < 4; ++in)
          unsafeAtomicAdd(orow + in * 16, acc[im][in][rr] * w);
      }
    }
  }
}

// ---------------- launch ----------------
extern "C" void kernel_launch(void* const* d_in, const int* in_sizes, int n_in,
                              void* d_out, int out_size, void* d_ws, size_t ws_size,
                              hipStream_t stream) {
  const float* x  = (const float*)d_in[0];   // [2,4096,1024]
  const float* gw = (const float*)d_in[1];   // [8,1024]
  const float* Wg = (const float*)d_in[2];   // [8,1024,2048]
  const float* Wu = (const float*)d_in[3];   // [8,1024,2048]
  const float* Wd = (const float*)d_in[4];   // [8,2048,1024]

  float* out    = (float*)d_out;             // [8192,1024]
  float* logits = out + (size_t)NTOK * HDIM; // [8192,8]

  char* p = (char*)d_ws;
  u16* Wgt = (u16*)p;  p += (size_t)NEXP * FDIM * HDIM * 2;            // [E][F][H] bf16
  u16* Wut = (u16*)p;  p += (size_t)NEXP * FDIM * HDIM * 2;
  u16* Wdt = (u16*)p;  p += (size_t)NEXP * HDIM * FDIM * 2;            // [E][H][F] bf16
  u16* Xg  = (u16*)p;  p += (size_t)(RTOT + RPAD) * HDIM * 2;          // gathered bf16 rows
  u16* G   = (u16*)p;  p += (size_t)(RTOT + RPAD) * FDIM * 2;          // silu(g)*u, bf16
  int*   tok_ids = (int*)p;   p += (RTOT + RPAD) * 4;
  float* wts     = (float*)p; p += (RTOT + RPAD) * 4;
  int*   te      = (int*)p;   p += NTOK * 2 * 4;
  float* tw      = (float*)p; p += NTOK * 2 * 4;
  int*   counts  = (int*)p;   p += NEXP * 4;
  int*   offs    = (int*)p;   p += (NEXP + 1) * 4;
  int*   cursors = (int*)p;   p += NEXP * 16 * 4;                      // 64B-strided

  hipMemsetAsync(out, 0, (size_t)NTOK * HDIM * sizeof(float), stream);
  hipMemsetAsync(counts, 0, NEXP * sizeof(int), stream);

  router_kernel<<<(NTOK * 64) / 256, 256, 0, stream>>>(x, gw, logits, te, tw);
  count_kernel<<<16, 256, 0, stream>>>(te, counts);
  prefix_kernel<<<1, 64, 0, stream>>>(counts, offs, cursors);
  scatter_kernel<<<NTOK / 256, 256, 0, stream>>>(te, tw, cursors, tok_ids, wts);
  gather_cast_kernel<<<RTOT, 256, 0, stream>>>(x, tok_ids, Xg);

  transpose_cast_kernel<<<dim3(FDIM / 64, HDIM / 64, NEXP), 256, 0, stream>>>(Wg, Wgt, HDIM, FDIM);
  transpose_cast_kernel<<<dim3(FDIM / 64, HDIM / 64, NEXP), 256, 0, stream>>>(Wu, Wut, HDIM, FDIM);
  transpose_cast_kernel<<<dim3(HDIM / 64, FDIM / 64, NEXP), 256, 0, stream>>>(Wd, Wdt, FDIM, HDIM);

  gemm1_kernel<<<dim3(FDIM / 128, 64, NEXP), 256, 0, stream>>>(Xg, Wgt, Wut, offs, G);
  gemm2_kernel<<<dim3(HDIM / 128, 64, NEXP), 256, 0, stream>>>(G, Wdt, offs, tok_ids, wts, out);
}

// Round 4
// 556.299 us; speedup vs baseline: 1.4356x; 1.0213x over previous
//
#include <hip/hip_runtime.h>
#include <cstdint>

// ---------------- problem constants ----------------
#define NTOK   8192        // B*S tokens
#define HDIM   1024        // hidden
#define FDIM   2048        // intermediate
#define NEXP   8
#define RTOT   (2*NTOK)    // routed rows (every token has exactly 2 experts)
#define RPAD   128         // tile-overrun padding rows

typedef unsigned short u16;
typedef short   bf16x8 __attribute__((ext_vector_type(8)));
typedef float   f32x4  __attribute__((ext_vector_type(4)));
typedef u16     u16x8  __attribute__((ext_vector_type(8)));

__device__ __forceinline__ u16 f2bf(float v) {
  union { float f; uint32_t u; } a; a.f = v;
  uint32_t r = a.u + 0x7FFFu + ((a.u >> 16) & 1u);   // RNE
  return (u16)(r >> 16);
}
__device__ __forceinline__ float bf2f(u16 b) {
  union { uint32_t u; float f; } a; a.u = ((uint32_t)b) << 16; return a.f;
}

// ---------------- router: logits, top-2 (NO global atomics) ----------------
__global__ void router_kernel(const float* __restrict__ x, const float* __restrict__ gw,
                              float* __restrict__ logits, int* __restrict__ te,
                              float* __restrict__ tw) {
  int gid  = blockIdx.x * blockDim.x + threadIdx.x;
  int t    = gid >> 6;
  int lane = gid & 63;
  const float4* xr = (const float4*)(x + (size_t)t * HDIM);
  float acc[NEXP];
#pragma unroll
  for (int e = 0; e < NEXP; ++e) acc[e] = 0.f;
#pragma unroll
  for (int c = 0; c < 4; ++c) {
    float4 xv = xr[c * 64 + lane];
#pragma unroll
    for (int e = 0; e < NEXP; ++e) {
      float4 wv = ((const float4*)(gw + e * HDIM))[c * 64 + lane];
      acc[e] += xv.x * wv.x + xv.y * wv.y + xv.z * wv.z + xv.w * wv.w;
    }
  }
#pragma unroll
  for (int off = 32; off > 0; off >>= 1)
#pragma unroll
    for (int e = 0; e < NEXP; ++e) acc[e] += __shfl_xor(acc[e], off, 64);

  if (lane == 0) {
#pragma unroll
    for (int e = 0; e < NEXP; ++e) logits[(size_t)t * NEXP + e] = acc[e];
    int e1 = 0;
#pragma unroll
    for (int e = 1; e < NEXP; ++e) if (acc[e] > acc[e1]) e1 = e;
    int e2 = -1;
#pragma unroll
    for (int e = 0; e < NEXP; ++e) {
      if (e == e1) continue;
      if (e2 < 0 || acc[e] > acc[e2]) e2 = e;
    }
    float m  = fmaxf(acc[e1], acc[e2]);
    float p1 = __expf(acc[e1] - m), p2 = __expf(acc[e2] - m);
    float inv = 1.f / (p1 + p2);
    te[t * 2]     = e1;  tw[t * 2]     = p1 * inv;
    te[t * 2 + 1] = e2;  tw[t * 2 + 1] = p2 * inv;
  }
}

// ---------------- fused count+prefix: single block, register histogram ----------------
__global__ void count_prefix_kernel(const int* __restrict__ te, int* __restrict__ offs,
                                    int* __restrict__ cursors) {
  __shared__ int wsum[16][NEXP];
  int cnt[NEXP];
#pragma unroll
  for (int e = 0; e < NEXP; ++e) cnt[e] = 0;
  for (int i = threadIdx.x; i < 2 * NTOK; i += 1024) {
    int v = te[i];
#pragma unroll
    for (int e = 0; e < NEXP; ++e) cnt[e] += (v == e) ? 1 : 0;
  }
#pragma unroll
  for (int off = 32; off > 0; off >>= 1)
#pragma unroll
    for (int e = 0; e < NEXP; ++e) cnt[e] += __shfl_xor(cnt[e], off, 64);
  int wave = threadIdx.x >> 6, lane = threadIdx.x & 63;
  if (lane == 0)
#pragma unroll
    for (int e = 0; e < NEXP; ++e) wsum[wave][e] = cnt[e];
  __syncthreads();
  if (threadIdx.x == 0) {
    int s = 0;
    for (int e = 0; e < NEXP; ++e) {
      int c = 0;
      for (int w = 0; w < 16; ++w) c += wsum[w][e];
      offs[e] = s; cursors[e * 16] = s; s += c;
    }
    offs[NEXP] = s;
  }
}

// ---------------- scatter: wave-aggregated atomics; also writes token->slot map ----------------
__global__ void scatter_kernel(const int* __restrict__ te, const float* __restrict__ tw,
                               int* __restrict__ cursors, int* __restrict__ tok_ids,
                               float* __restrict__ wts, int* __restrict__ slots) {
  int t    = blockIdx.x * blockDim.x + threadIdx.x;
  int lane = threadIdx.x & 63;
#pragma unroll
  for (int s = 0; s < 2; ++s) {
    int   e = te[t * 2 + s];
    float w = tw[t * 2 + s];
    int pos = 0;
#pragma unroll
    for (int e0 = 0; e0 < NEXP; ++e0) {
      unsigned long long m = __ballot(e == e0);
      if (e == e0) {
        int leader = __ffsll((unsigned long long)m) - 1;
        int rank   = __popcll(m & ((1ull << lane) - 1ull));
        int b = 0;
        if (lane == leader) b = atomicAdd(&cursors[e0 * 16], (int)__popcll(m));
        b = __shfl(b, leader, 64);
        pos = b + rank;
      }
    }
    tok_ids[pos] = t;
    wts[pos] = w;
    slots[t * 2 + s] = pos;
  }
}

// ---------------- gather + cast X rows to bf16 (expert-sorted) ----------------
__global__ void gather_cast_kernel(const float* __restrict__ x, const int* __restrict__ tok_ids,
                                   u16* __restrict__ Xg) {
  int j = blockIdx.x;
  int t = tok_ids[j];
  float4 v = ((const float4*)(x + (size_t)t * HDIM))[threadIdx.x];
  ushort4 o;
  o.x = f2bf(v.x); o.y = f2bf(v.y); o.z = f2bf(v.z); o.w = f2bf(v.w);
  ((ushort4*)(Xg + (size_t)j * HDIM))[threadIdx.x] = o;
}

// ---------------- fused weight prep: [E][K][N] f32 -> [E][N][K] bf16, all 3 matrices ----------------
// grid (32,16,24): z = mat*8+expert; Wg/Wu: K=H,N=F (tn=bx,tk=by); Wd: K=F,N=H (tn=by,tk=bx)
__global__ __launch_bounds__(256)
void prep_weights_kernel(const float* __restrict__ Wg, const float* __restrict__ Wu,
                         const float* __restrict__ Wd, u16* __restrict__ Wgt,
                         u16* __restrict__ Wut, u16* __restrict__ Wdt) {
  __shared__ float tile[64 * 65];
  const int mat = blockIdx.z >> 3;
  const int e   = blockIdx.z & 7;
  const int K   = (mat < 2) ? HDIM : FDIM;
  const int N   = (mat < 2) ? FDIM : HDIM;
  const float* src = ((mat == 0) ? Wg : (mat == 1) ? Wu : Wd) + (size_t)e * K * N;
  u16*         dst = ((mat == 0) ? Wgt : (mat == 1) ? Wut : Wdt) + (size_t)e * K * N;
  const int tn = (mat < 2) ? blockIdx.x : blockIdx.y;
  const int tk = (mat < 2) ? blockIdx.y : blockIdx.x;
  const int k0 = tk * 64, n0 = tn * 64;

  // phase 1: read 64x64 f32 (float4, coalesced along n), store rows to LDS
  const int r  = threadIdx.x >> 2;       // k within tile, 0..63
  const int c4 = threadIdx.x & 3;
#pragma unroll
  for (int i = 0; i < 4; ++i) {
    int c = (c4 + i * 4) * 4;            // covers 0..60 step 4
    float4 v = *(const float4*)(src + (size_t)(k0 + r) * N + n0 + c);
    tile[r * 65 + c]     = v.x;
    tile[r * 65 + c + 1] = v.y;
    tile[r * 65 + c + 2] = v.z;
    tile[r * 65 + c + 3] = v.w;
  }
  __syncthreads();

  // phase 2: read columns (2-way bank alias only), pack bf16 x8, 16B stores (coalesced along k)
  const int kq = threadIdx.x & 7;        // 8 threads per output row
  const int nr = threadIdx.x >> 3;       // 0..31
#pragma unroll
  for (int p = 0; p < 2; ++p) {
    int n = p * 32 + nr;
    u16x8 pk;
#pragma unroll
    for (int j = 0; j < 8; ++j)
      pk[j] = f2bf(tile[(kq * 8 + j) * 65 + n]);
    *(u16x8*)(dst + (size_t)(n0 + n) * K + k0 + kq * 8) = pk;
  }
}

// ---------------- GEMM staging: 128x64 bf16 tile via global_load_lds (width 16) ----------------
// LDS layout: elem (row,k) stored at row*64 + (k ^ ((row&7)<<3))  -> ds_read_b128 is 2-way max
__device__ __forceinline__ void stage_tile(const u16* __restrict__ src, int ld,
                                           u16* __restrict__ lds, int wave, int lane) {
#pragma unroll
  for (int i = 0; i < 4; ++i) {
    int chunk = ((i << 2) + wave) << 9;       // wave-uniform LDS base (elems)
    int flat  = chunk + (lane << 3);
    int row   = flat >> 6;
    int km    = (flat & 63) ^ ((row & 7) << 3);
    __builtin_amdgcn_global_load_lds(
        (const __attribute__((address_space(1))) uint32_t*)(src + (size_t)row * ld + km),
        (__attribute__((address_space(3))) uint32_t*)(lds + chunk),
        16, 0, 0);
  }
}

// ---------------- GEMM1: G = silu(Xg @ WgT^T) * (Xg @ WuT^T), bf16 out ----------------
__global__ __launch_bounds__(256, 2)
void gemm1_kernel(const u16* __restrict__ Xg, const u16* __restrict__ Wgt,
                  const u16* __restrict__ Wut, const int* __restrict__ offs,
                  u16* __restrict__ G) {
  const int e     = blockIdx.z;
  const int rbase = offs[e];
  const int rows  = offs[e + 1] - rbase;
  const int row0  = blockIdx.y * 128;
  if (row0 >= rows) return;
  const int n0    = blockIdx.x * 128;
  const int arow0 = rbase + row0;

  __shared__ __align__(16) u16 As[128 * 64];
  __shared__ __align__(16) u16 Bgs[128 * 64];
  __shared__ __align__(16) u16 Bus[128 * 64];

  const int tid  = threadIdx.x;
  const int wave = tid >> 6;
  const int lane = tid & 63;
  const int wm   = wave >> 1, wn = wave & 1;
  const int l15  = lane & 15, quad = lane >> 4;

  const u16* Ag = Xg  + (size_t)arow0 * HDIM;
  const u16* Bg = Wgt + (size_t)e * FDIM * HDIM + (size_t)n0 * HDIM;
  const u16* Bu = Wut + (size_t)e * FDIM * HDIM + (size_t)n0 * HDIM;

  f32x4 accg[4][4], accu[4][4];
#pragma unroll
  for (int i = 0; i < 4; ++i)
#pragma unroll
    for (int j = 0; j < 4; ++j) { accg[i][j] = (f32x4)0.f; accu[i][j] = (f32x4)0.f; }

  for (int kt = 0; kt < HDIM / 64; ++kt) {
    const int k0 = kt * 64;
    stage_tile(Ag + k0, HDIM, As,  wave, lane);
    stage_tile(Bg + k0, HDIM, Bgs, wave, lane);
    stage_tile(Bu + k0, HDIM, Bus, wave, lane);
    __syncthreads();
#pragma unroll
    for (int kk = 0; kk < 64; kk += 32) {
      bf16x8 af[4];
#pragma unroll
      for (int im = 0; im < 4; ++im) {
        int r  = wm * 64 + im * 16 + l15;
        int kq = (kk + quad * 8) ^ ((r & 7) << 3);
        af[im] = *(const bf16x8*)(As + r * 64 + kq);
      }
#pragma unroll
      for (int in = 0; in < 4; ++in) {
        int r  = wn * 64 + in * 16 + l15;
        int kq = (kk + quad * 8) ^ ((r & 7) << 3);
        bf16x8 bg = *(const bf16x8*)(Bgs + r * 64 + kq);
        bf16x8 bu = *(const bf16x8*)(Bus + r * 64 + kq);
#pragma unroll
        for (int im = 0; im < 4; ++im) {
          accg[im][in] = __builtin_amdgcn_mfma_f32_16x16x32_bf16(af[im], bg, accg[im][in], 0, 0, 0);
          accu[im][in] = __builtin_amdgcn_mfma_f32_16x16x32_bf16(af[im], bu, accu[im][in], 0, 0, 0);
        }
      }
    }
    __syncthreads();
  }

  // epilogue: silu(g)*u -> bf16 G[row][n]
#pragma unroll
  for (int im = 0; im < 4; ++im) {
#pragma unroll
    for (int rr = 0; rr < 4; ++rr) {
      int lrow = row0 + wm * 64 + im * 16 + quad * 4 + rr;
      if (lrow < rows) {
        size_t grow = (size_t)(rbase + lrow);
#pragma unroll
        for (int in = 0; in < 4; ++in) {
          float g = accg[im][in][rr];
          float u = accu[im][in][rr];
          float val = g / (1.f + __expf(-g)) * u;
          int gcol = n0 + wn * 64 + in * 16 + l15;
          G[grow * FDIM + gcol] = f2bf(val);
        }
      }
    }
  }
}

// ---------------- GEMM2: Y[grow] = w[grow] * (G[grow] @ Wd^T), bf16, NO atomics ----------------
__global__ __launch_bounds__(256, 2)
void gemm2_kernel(const u16* __restrict__ G, const u16* __restrict__ Wdt,
                  const int* __restrict__ offs, const float* __restrict__ wts,
                  u16* __restrict__ Y) {
  const int e     = blockIdx.z;
  const int rbase = offs[e];
  const int rows  = offs[e + 1] - rbase;
  const int row0  = blockIdx.y * 128;
  if (row0 >= rows) return;
  const int n0    = blockIdx.x * 128;
  const int arow0 = rbase + row0;

  __shared__ __align__(16) u16 As[128 * 64];
  __shared__ __align__(16) u16 Bs[128 * 64];

  const int tid  = threadIdx.x;
  const int wave = tid >> 6;
  const int lane = tid & 63;
  const int wm   = wave >> 1, wn = wave & 1;
  const int l15  = lane & 15, quad = lane >> 4;

  const u16* Ag = G   + (size_t)arow0 * FDIM;
  const u16* Bg = Wdt + (size_t)e * HDIM * FDIM + (size_t)n0 * FDIM;

  f32x4 acc[4][4];
#pragma unroll
  for (int i = 0; i < 4; ++i)
#pragma unroll
    for (int j = 0; j < 4; ++j) acc[i][j] = (f32x4)0.f;

  for (int kt = 0; kt < FDIM / 64; ++kt) {
    const int k0 = kt * 64;
    stage_tile(Ag + k0, FDIM, As, wave, lane);
    stage_tile(Bg + k0, FDIM, Bs, wave, lane);
    __syncthreads();
#pragma unroll
    for (int kk = 0; kk < 64; kk += 32) {
      bf16x8 af[4], bf[4];
#pragma unroll
      for (int im = 0; im < 4; ++im) {
        int r  = wm * 64 + im * 16 + l15;
        int kq = (kk + quad * 8) ^ ((r & 7) << 3);
        af[im] = *(const bf16x8*)(As + r * 64 + kq);
      }
#pragma unroll
      for (int in = 0; in < 4; ++in) {
        int r  = wn * 64 + in * 16 + l15;
        int kq = (kk + quad * 8) ^ ((r & 7) << 3);
        bf[in] = *(const bf16x8*)(Bs + r * 64 + kq);
      }
#pragma unroll
      for (int in = 0; in < 4; ++in)
#pragma unroll
        for (int im = 0; im < 4; ++im)
          acc[im][in] = __builtin_amdgcn_mfma_f32_16x16x32_bf16(af[im], bf[in], acc[im][in], 0, 0, 0);
    }
    __syncthreads();
  }

#pragma unroll
  for (int im = 0; im < 4; ++im) {
#pragma unroll
    for (int rr = 0; rr < 4; ++rr) {
      int lrow = row0 + wm * 64 + im * 16 + quad * 4 + rr;
      if (lrow < rows) {
        int grow = rbase + lrow;
        float w  = wts[grow];
        u16* yrow = Y + (size_t)grow * HDIM + n0 + wn * 64 + l15;
#pragma unroll
        for (int in = 0; in < 4; ++in)
          yrow[in * 16] = f2bf(acc[im][in][rr] * w);
      }
    }
  }
}

// ---------------- combine: out[t] = Y[slot0(t)] + Y[slot1(t)] ----------------
__global__ void combine_kernel(const u16* __restrict__ Y, const int* __restrict__ slots,
                               float* __restrict__ out) {
  int t  = blockIdx.x;
  int s1 = slots[2 * t], s2 = slots[2 * t + 1];
  ushort4 a = ((const ushort4*)(Y + (size_t)s1 * HDIM))[threadIdx.x];
  ushort4 b = ((const ushort4*)(Y + (size_t)s2 * HDIM))[threadIdx.x];
  float4 o;
  o.x = bf2f(a.x) + bf2f(b.x);
  o.y = bf2f(a.y) + bf2f(b.y);
  o.z = bf2f(a.z) + bf2f(b.z);
  o.w = bf2f(a.w) + bf2f(b.w);
  ((float4*)(out + (size_t)t * HDIM))[threadIdx.x] = o;
}

// ---------------- launch ----------------
extern "C" void kernel_launch(void* const* d_in, const int* in_sizes, int n_in,
                              void* d_out, int out_size, void* d_ws, size_t ws_size,
                              hipStream_t stream) {
  const float* x  = (const float*)d_in[0];   // [2,4096,1024]
  const float* gw = (const float*)d_in[1];   // [8,1024]
  const float* Wg = (const float*)d_in[2];   // [8,1024,2048]
  const float* Wu = (const float*)d_in[3];   // [8,1024,2048]
  const float* Wd = (const float*)d_in[4];   // [8,2048,1024]

  float* out    = (float*)d_out;             // [8192,1024]
  float* logits = out + (size_t)NTOK * HDIM; // [8192,8]

  char* p = (char*)d_ws;
  u16* Wgt = (u16*)p;  p += (size_t)NEXP * FDIM * HDIM * 2;            // [E][F][H] bf16
  u16* Wut = (u16*)p;  p += (size_t)NEXP * FDIM * HDIM * 2;
  u16* Wdt = (u16*)p;  p += (size_t)NEXP * HDIM * FDIM * 2;            // [E][H][F] bf16
  u16* Xg  = (u16*)p;  p += (size_t)(RTOT + RPAD) * HDIM * 2;          // gathered bf16 rows
  u16* G   = (u16*)p;  p += (size_t)(RTOT + RPAD) * FDIM * 2;          // silu(g)*u, bf16
  int*   tok_ids = (int*)p;   p += (RTOT + RPAD) * 4;
  float* wts     = (float*)p; p += (RTOT + RPAD) * 4;
  int*   te      = (int*)p;   p += NTOK * 2 * 4;
  float* tw      = (float*)p; p += NTOK * 2 * 4;
  int*   slots   = (int*)p;   p += NTOK * 2 * 4;
  int*   offs    = (int*)p;   p += (NEXP + 1) * 4;
  int*   cursors = (int*)p;   p += NEXP * 16 * 4;                      // 64B-strided

  u16* Y = Xg;   // Xg is dead after gemm1; gemm2's per-row output aliases it

  router_kernel<<<(NTOK * 64) / 256, 256, 0, stream>>>(x, gw, logits, te, tw);
  count_prefix_kernel<<<1, 1024, 0, stream>>>(te, offs, cursors);
  scatter_kernel<<<NTOK / 256, 256, 0, stream>>>(te, tw, cursors, tok_ids, wts, slots);
  gather_cast_kernel<<<RTOT, 256, 0, stream>>>(x, tok_ids, Xg);

  prep_weights_kernel<<<dim3(32, 16, 24), 256, 0, stream>>>(Wg, Wu, Wd, Wgt, Wut, Wdt);

  gemm1_kernel<<<dim3(FDIM / 128, 64, NEXP), 256, 0, stream>>>(Xg, Wgt, Wut, offs, G);
  gemm2_kernel<<<dim3(HDIM / 128, 64, NEXP), 256, 0, stream>>>(G, Wdt, offs, wts, Y);
  combine_kernel<<<NTOK, 256, 0, stream>>>(Y, slots, out);
}